// Round 4
// baseline (15247.853 us; speedup 1.0000x reference)
//
#include <hip/hip_runtime.h>

// Problem constants
#define BB 16
#define TT 4096
#define DD 256     // DIM
#define HH 128     // hidden
#define G3 384     // 3*H
#define MM (BB*TT) // 65536 rows

typedef unsigned short u16;
typedef unsigned int u32;
typedef __attribute__((ext_vector_type(8))) short short8;  // 8 bf16 (4 VGPRs)
typedef __attribute__((ext_vector_type(4))) float f32x4;

__device__ __forceinline__ float bf2f(u16 u) {
    return __uint_as_float(((u32)u) << 16);
}
__device__ __forceinline__ u16 f2bf(float f) {
    u32 u = __float_as_uint(f);
    u32 lsb = (u >> 16) & 1u;
    u += 0x7fffu + lsb;      // RNE
    return (u16)(u >> 16);
}

// ---------------- Input-projection GEMM (fp32) ----------------
// XG[dir][m][0:384] = X[m][0:256] @ Wi[dir][0:256][0:384]
#define Bb 128
#define Bn 128
#define Bk 16

__global__ __launch_bounds__(256) void gemm_in(const float* __restrict__ X,
                                               const float* __restrict__ Wi,
                                               float* __restrict__ XG) {
    __shared__ __align__(16) float As[Bk][Bb + 4];
    __shared__ __align__(16) float Bs[Bk][Bn + 4];
    const int tid = threadIdx.x;
    const int m0  = blockIdx.y * Bb;
    const int nb  = blockIdx.x;
    const int n0  = nb * Bn;
    const int dir = (n0 >= G3) ? 1 : 0;
    const int nloc0 = n0 - dir * G3;
    const float* Wd = Wi + (size_t)dir * DD * G3;

    const int tx = tid & 15;
    const int ty = tid >> 4;
    float acc[8][8];
    #pragma unroll
    for (int i = 0; i < 8; ++i)
        #pragma unroll
        for (int j = 0; j < 8; ++j) acc[i][j] = 0.f;

    for (int k0 = 0; k0 < DD; k0 += Bk) {
        #pragma unroll
        for (int p = 0; p < 2; ++p) {
            int idx = tid + p * 256;
            int row = idx >> 2;
            int c4  = (idx & 3) * 4;
            float4 v = *(const float4*)(X + (size_t)(m0 + row) * DD + k0 + c4);
            As[c4 + 0][row] = v.x;
            As[c4 + 1][row] = v.y;
            As[c4 + 2][row] = v.z;
            As[c4 + 3][row] = v.w;
        }
        #pragma unroll
        for (int p = 0; p < 2; ++p) {
            int idx  = tid + p * 256;
            int krow = idx >> 5;
            int c4   = (idx & 31) * 4;
            float4 v = *(const float4*)(Wd + (size_t)(k0 + krow) * G3 + nloc0 + c4);
            *(float4*)(&Bs[krow][c4]) = v;
        }
        __syncthreads();
        #pragma unroll
        for (int k = 0; k < Bk; ++k) {
            float4 a0 = *(const float4*)(&As[k][ty * 8]);
            float4 a1 = *(const float4*)(&As[k][ty * 8 + 4]);
            float4 b0 = *(const float4*)(&Bs[k][tx * 8]);
            float4 b1 = *(const float4*)(&Bs[k][tx * 8 + 4]);
            float av[8] = {a0.x, a0.y, a0.z, a0.w, a1.x, a1.y, a1.z, a1.w};
            float bv[8] = {b0.x, b0.y, b0.z, b0.w, b1.x, b1.y, b1.z, b1.w};
            #pragma unroll
            for (int i = 0; i < 8; ++i)
                #pragma unroll
                for (int j = 0; j < 8; ++j) acc[i][j] += av[i] * bv[j];
        }
        __syncthreads();
    }
    #pragma unroll
    for (int i = 0; i < 8; ++i) {
        int m = m0 + ty * 8 + i;
        float* dst = XG + ((size_t)dir * MM + m) * G3 + nloc0 + tx * 8;
        *(float4*)dst       = make_float4(acc[i][0], acc[i][1], acc[i][2], acc[i][3]);
        *(float4*)(dst + 4) = make_float4(acc[i][4], acc[i][5], acc[i][6], acc[i][7]);
    }
}

// ---------------- MFMA recurrence ----------------
__device__ __forceinline__ float fast_sigmoid(float x) {
    float e = __expf(-x);
    return __builtin_amdgcn_rcpf(1.f + e);
}
__device__ __forceinline__ float fast_tanh(float x) {
    float e = __expf(2.f * x);
    return 1.f - 2.f * __builtin_amdgcn_rcpf(1.f + e);
}

// grid = 2 (dir); block = 512 (8 waves). Wave w owns hcol in [16w,16w+16).
// Per step: acc[g] = h @ Wh[:, g*128+hcol-tile] via MFMA 16x16x32 bf16 (hi/lo
// split for ~fp32 accuracy). Gates r,z,n for a (batch,hcol) all land in the
// same lane/reg -> in-register h update. h broadcast via LDS bf16 hi/lo
// ping-pong buffers; one raw s_barrier per step (no vmcnt drain, so xg
// prefetch and out stores stay in flight).
__global__ __launch_bounds__(512, 2) void gru_rec(const float* __restrict__ XG,
                                                  const float* __restrict__ Wh,
                                                  const float* __restrict__ bh,
                                                  float* __restrict__ Xout) {
    const int dir  = blockIdx.x;
    const int tid  = threadIdx.x;
    const int lane = tid & 63;
    const int wave = tid >> 6;          // 0..7
    const int q    = lane >> 4;         // 0..3
    const int c    = lane & 15;
    const int hcol = wave * 16 + c;     // 0..127

    // [ping][hi/lo][batch][hcol] ; row stride 136 u16 = 272 B (16B multiple)
    __shared__ __align__(16) u16 hbuf[2][2][16][136];

    // ---- preload B-fragments (Wh) split hi/lo ----
    // B layout (16x16x32): n = lane&15 (-> tile col), k = (lane>>4)*8 + j
    short8 bhi[3][4], blo[3][4];
    const float* W = Wh + (size_t)dir * HH * G3;
    #pragma unroll
    for (int g = 0; g < 3; ++g) {
        const int n = g * 128 + hcol;
        #pragma unroll
        for (int ch = 0; ch < 4; ++ch) {
            short8 vh, vl;
            #pragma unroll
            for (int j = 0; j < 8; ++j) {
                int k = ch * 32 + q * 8 + j;
                float w = W[(size_t)k * G3 + n];
                u16 hi = f2bf(w);
                u16 lo = f2bf(w - bf2f(hi));
                vh[j] = (short)hi;
                vl[j] = (short)lo;
            }
            bhi[g][ch] = vh;
            blo[g][ch] = vl;
        }
    }
    float bias[3];
    #pragma unroll
    for (int g = 0; g < 3; ++g) bias[g] = bh[dir * G3 + g * 128 + hcol];

    // A-fragments of h_t (zero at t=0); A layout: m = lane&15, k = (lane>>4)*8+j
    short8 ahi[4], alo[4];
    #pragma unroll
    for (int ch = 0; ch < 4; ++ch) {
        #pragma unroll
        for (int j = 0; j < 8; ++j) { ahi[ch][j] = 0; alo[ch][j] = 0; }
    }
    float ho[4] = {0.f, 0.f, 0.f, 0.f};   // h_old at (b=q*4+r, hcol), fp32 exact

    const int tstep = dir ? -1 : 1;
    const int t0    = dir ? (TT - 1) : 0;

    size_t rowb[4];
    float* outb[4];
    #pragma unroll
    for (int r = 0; r < 4; ++r) {
        rowb[r] = ((size_t)dir * MM + (size_t)(q * 4 + r) * TT) * G3;
        outb[r] = Xout + (size_t)(q * 4 + r) * TT * DD + dir * HH + hcol;
    }

    // initial xg loads (t0)
    float xr[4], xz[4], xn[4];
    #pragma unroll
    for (int r = 0; r < 4; ++r) {
        size_t base = rowb[r] + (size_t)t0 * G3 + hcol;
        xr[r] = XG[base];
        xz[r] = XG[base + 128];
        xn[r] = XG[base + 256];
    }

    for (int t = 0; t < TT; ++t) {
        const int tt = t0 + t * tstep;

        // prefetch next step's xg (stays in flight across the raw barrier)
        float nr[4], nz[4], nn_[4];
        if (t + 1 < TT) {
            const int tn = tt + tstep;
            #pragma unroll
            for (int r = 0; r < 4; ++r) {
                size_t base = rowb[r] + (size_t)tn * G3 + hcol;
                nr[r]  = XG[base];
                nz[r]  = XG[base + 128];
                nn_[r] = XG[base + 256];
            }
        }

        // MFMA: 3 gates x (2 half-K chains of 6)
        f32x4 acc[3];
        #pragma unroll
        for (int g = 0; g < 3; ++g) {
            f32x4 a0 = {0.f, 0.f, 0.f, 0.f};
            f32x4 a1 = {0.f, 0.f, 0.f, 0.f};
            a0 = __builtin_amdgcn_mfma_f32_16x16x32_bf16(ahi[0], bhi[g][0], a0, 0, 0, 0);
            a0 = __builtin_amdgcn_mfma_f32_16x16x32_bf16(ahi[1], bhi[g][1], a0, 0, 0, 0);
            a0 = __builtin_amdgcn_mfma_f32_16x16x32_bf16(alo[0], bhi[g][0], a0, 0, 0, 0);
            a0 = __builtin_amdgcn_mfma_f32_16x16x32_bf16(alo[1], bhi[g][1], a0, 0, 0, 0);
            a0 = __builtin_amdgcn_mfma_f32_16x16x32_bf16(ahi[0], blo[g][0], a0, 0, 0, 0);
            a0 = __builtin_amdgcn_mfma_f32_16x16x32_bf16(ahi[1], blo[g][1], a0, 0, 0, 0);
            a1 = __builtin_amdgcn_mfma_f32_16x16x32_bf16(ahi[2], bhi[g][2], a1, 0, 0, 0);
            a1 = __builtin_amdgcn_mfma_f32_16x16x32_bf16(ahi[3], bhi[g][3], a1, 0, 0, 0);
            a1 = __builtin_amdgcn_mfma_f32_16x16x32_bf16(alo[2], bhi[g][2], a1, 0, 0, 0);
            a1 = __builtin_amdgcn_mfma_f32_16x16x32_bf16(alo[3], bhi[g][3], a1, 0, 0, 0);
            a1 = __builtin_amdgcn_mfma_f32_16x16x32_bf16(ahi[2], blo[g][2], a1, 0, 0, 0);
            a1 = __builtin_amdgcn_mfma_f32_16x16x32_bf16(ahi[3], blo[g][3], a1, 0, 0, 0);
            acc[g] = a0 + a1;
        }

        // gates + h update, fully in-register (C layout: col=lane&15 -> hcol,
        // row=(lane>>4)*4+reg -> batch), then write h_{t+1} to LDS + out
        const int pb = (t + 1) & 1;
        #pragma unroll
        for (int r = 0; r < 4; ++r) {
            float pr = acc[0][r] + xr[r] + bias[0];
            float pz = acc[1][r] + xz[r] + bias[1];
            float pm = acc[2][r] + bias[2];
            float rg = fast_sigmoid(pr);
            float zg = fast_sigmoid(pz);
            float ng = fast_tanh(xn[r] + rg * pm);
            float hn = (1.f - zg) * ng + zg * ho[r];
            ho[r] = hn;
            outb[r][(size_t)tt * DD] = hn;
            u16 hi = f2bf(hn);
            u16 lo = f2bf(hn - bf2f(hi));
            hbuf[pb][0][q * 4 + r][hcol] = hi;
            hbuf[pb][1][q * 4 + r][hcol] = lo;
        }

        // wait LDS writes only, then barrier (vmcnt stays outstanding)
        asm volatile("s_waitcnt lgkmcnt(0)\n\ts_barrier" ::: "memory");

        if (t + 1 < TT) {
            const u16* hp = &hbuf[pb][0][c][0];
            const u16* lp = &hbuf[pb][1][c][0];
            #pragma unroll
            for (int ch = 0; ch < 4; ++ch) {
                ahi[ch] = *(const short8*)(hp + ch * 32 + q * 8);
                alo[ch] = *(const short8*)(lp + ch * 32 + q * 8);
            }
            #pragma unroll
            for (int r = 0; r < 4; ++r) {
                xr[r] = nr[r];
                xz[r] = nz[r];
                xn[r] = nn_[r];
            }
        }
    }
}

// ---------------- Launch ----------------
// ws: XG only = 2*65536*384*4 = 201.3 MB. Inter-layer activations ping-pong
// through d_out (each layer fully rewrites it before the next reads it).
extern "C" void kernel_launch(void* const* d_in, const int* in_sizes, int n_in,
                              void* d_out, int out_size, void* d_ws, size_t ws_size,
                              hipStream_t stream) {
    const float* x  = (const float*)d_in[0];   // [16,4096,256]
    const float* Wi = (const float*)d_in[1];   // [3,2,256,384]
    const float* Wh = (const float*)d_in[2];   // [3,2,128,384]
    const float* bh = (const float*)d_in[3];   // [3,2,384]
    float* out = (float*)d_out;                // [16,4096,256]

    float* XG = (float*)d_ws;                  // [2, 65536, 384] fp32

    for (int l = 0; l < 3; ++l) {
        const float* in  = (l == 0) ? x : out;
        const float* Wil = Wi + (size_t)l * 2 * DD * G3;
        const float* Whl = Wh + (size_t)l * 2 * HH * G3;
        const float* bhl = bh + (size_t)l * 2 * G3;

        gemm_in<<<dim3(6, MM / Bb), 256, 0, stream>>>(in, Wil, XG);
        gru_rec<<<2, 512, 0, stream>>>(XG, Whl, bhl, out);
    }
}

// Round 5
// 10215.183 us; speedup vs baseline: 1.4927x; 1.4927x over previous
//
#include <hip/hip_runtime.h>

// Problem constants
#define BB 16
#define TT 4096
#define DD 256     // DIM
#define HH 128     // hidden
#define G3 384     // 3*H
#define MM (BB*TT) // 65536 rows

typedef unsigned short u16;
typedef unsigned int u32;
typedef __attribute__((ext_vector_type(8))) short short8;  // 8 bf16 (4 VGPRs)
typedef __attribute__((ext_vector_type(4))) float f32x4;

__device__ __forceinline__ float bf2f(u16 u) {
    return __uint_as_float(((u32)u) << 16);
}
__device__ __forceinline__ u16 f2bf(float f) {
    u32 u = __float_as_uint(f);
    u32 lsb = (u >> 16) & 1u;
    u += 0x7fffu + lsb;      // RNE
    return (u16)(u >> 16);
}

// ---------------- Input-projection GEMM (fp32) ----------------
// XG[dir][m][0:384] = X[m][0:256] @ Wi[dir][0:256][0:384]
#define Bb 128
#define Bn 128
#define Bk 16

__global__ __launch_bounds__(256) void gemm_in(const float* __restrict__ X,
                                               const float* __restrict__ Wi,
                                               float* __restrict__ XG) {
    __shared__ __align__(16) float As[Bk][Bb + 4];
    __shared__ __align__(16) float Bs[Bk][Bn + 4];
    const int tid = threadIdx.x;
    const int m0  = blockIdx.y * Bb;
    const int nb  = blockIdx.x;
    const int n0  = nb * Bn;
    const int dir = (n0 >= G3) ? 1 : 0;
    const int nloc0 = n0 - dir * G3;
    const float* Wd = Wi + (size_t)dir * DD * G3;

    const int tx = tid & 15;
    const int ty = tid >> 4;
    float acc[8][8];
    #pragma unroll
    for (int i = 0; i < 8; ++i)
        #pragma unroll
        for (int j = 0; j < 8; ++j) acc[i][j] = 0.f;

    for (int k0 = 0; k0 < DD; k0 += Bk) {
        #pragma unroll
        for (int p = 0; p < 2; ++p) {
            int idx = tid + p * 256;
            int row = idx >> 2;
            int c4  = (idx & 3) * 4;
            float4 v = *(const float4*)(X + (size_t)(m0 + row) * DD + k0 + c4);
            As[c4 + 0][row] = v.x;
            As[c4 + 1][row] = v.y;
            As[c4 + 2][row] = v.z;
            As[c4 + 3][row] = v.w;
        }
        #pragma unroll
        for (int p = 0; p < 2; ++p) {
            int idx  = tid + p * 256;
            int krow = idx >> 5;
            int c4   = (idx & 31) * 4;
            float4 v = *(const float4*)(Wd + (size_t)(k0 + krow) * G3 + nloc0 + c4);
            *(float4*)(&Bs[krow][c4]) = v;
        }
        __syncthreads();
        #pragma unroll
        for (int k = 0; k < Bk; ++k) {
            float4 a0 = *(const float4*)(&As[k][ty * 8]);
            float4 a1 = *(const float4*)(&As[k][ty * 8 + 4]);
            float4 b0 = *(const float4*)(&Bs[k][tx * 8]);
            float4 b1 = *(const float4*)(&Bs[k][tx * 8 + 4]);
            float av[8] = {a0.x, a0.y, a0.z, a0.w, a1.x, a1.y, a1.z, a1.w};
            float bv[8] = {b0.x, b0.y, b0.z, b0.w, b1.x, b1.y, b1.z, b1.w};
            #pragma unroll
            for (int i = 0; i < 8; ++i)
                #pragma unroll
                for (int j = 0; j < 8; ++j) acc[i][j] += av[i] * bv[j];
        }
        __syncthreads();
    }
    #pragma unroll
    for (int i = 0; i < 8; ++i) {
        int m = m0 + ty * 8 + i;
        float* dst = XG + ((size_t)dir * MM + m) * G3 + nloc0 + tx * 8;
        *(float4*)dst       = make_float4(acc[i][0], acc[i][1], acc[i][2], acc[i][3]);
        *(float4*)(dst + 4) = make_float4(acc[i][4], acc[i][5], acc[i][6], acc[i][7]);
    }
}

// ---------------- MFMA recurrence, one WG per (dir,batch) ----------------
__device__ __forceinline__ float fast_sigmoid(float x) {
    float e = __expf(-x);
    return __builtin_amdgcn_rcpf(1.f + e);
}
__device__ __forceinline__ float fast_tanh(float x) {
    float e = __expf(2.f * x);
    return 1.f - 2.f * __builtin_amdgcn_rcpf(1.f + e);
}

// grid = 32 (dir,batch); block = 512 (8 waves). Wave w owns hcol slice
// [16w,16w+16) for ALL 3 gates (n = g*128 + hcol). M=1 trick: all 16 A-rows
// carry the same h vector, so every C row/reg holds the same valid gate value
// -> no masking, broadcast LDS reads, gates computed once per column.
// h kept as bf16 hi+lo (matches fp32 absmax in rounds 3/4).
__global__ __launch_bounds__(512, 2) void gru_rec(const float* __restrict__ XG,
                                                  const float* __restrict__ Wh,
                                                  const float* __restrict__ bh,
                                                  float* __restrict__ Xout) {
    const int wg   = blockIdx.x;     // 0..31
    const int dir  = wg & 1;
    const int b    = wg >> 1;
    const int tid  = threadIdx.x;
    const int lane = tid & 63;
    const int wave = tid >> 6;       // 0..7
    const int q    = lane >> 4;      // 0..3
    const int c    = lane & 15;
    const int hcol = wave * 16 + c;  // 0..127

    __shared__ __align__(16) u16 hhi[2][HH];   // ping-pong, bf16 hi
    __shared__ __align__(16) u16 hlo[2][HH];   // bf16 lo

    // ---- B-frag preload (Wh), hi/lo split ----
    // B layout (16x16x32): n = lane&15, k = (lane>>4)*8 + j
    short8 bhi[3][4], blo[3][4];
    const float* W = Wh + (size_t)dir * HH * G3;
    #pragma unroll
    for (int g = 0; g < 3; ++g) {
        const int n = g * 128 + hcol;
        #pragma unroll
        for (int ch = 0; ch < 4; ++ch) {
            short8 vh, vl;
            #pragma unroll
            for (int j = 0; j < 8; ++j) {
                int k = ch * 32 + q * 8 + j;
                float wv = W[(size_t)k * G3 + n];
                u16 hi = f2bf(wv);
                u16 lo = f2bf(wv - bf2f(hi));
                vh[j] = (short)hi;
                vl[j] = (short)lo;
            }
            bhi[g][ch] = vh;
            blo[g][ch] = vl;
        }
    }
    float bias[3];
    #pragma unroll
    for (int g = 0; g < 3; ++g) bias[g] = bh[dir * G3 + g * 128 + hcol];

    // A-frags of h_t (zero at t=0)
    short8 ahi[4], alo[4];
    #pragma unroll
    for (int ch = 0; ch < 4; ++ch) {
        #pragma unroll
        for (int j = 0; j < 8; ++j) { ahi[ch][j] = 0; alo[ch][j] = 0; }
    }
    float ho = 0.f;                  // h_old at this wave's column hcol

    const int t0    = dir ? (TT - 1) : 0;
    const int gstep = dir ? -G3 : G3;   // xg pointer step (floats)
    const int ostep = dir ? -DD : DD;   // out pointer step (floats)

    const float* xp = XG + ((size_t)dir * MM + (size_t)b * TT + t0) * G3 + hcol;
    float* op = Xout + ((size_t)b * TT + t0) * DD + dir * HH + hcol;

    // initial xg load (t0)
    float xr = xp[0], xz = xp[128], xn = xp[256];

    for (int t = 0; t < TT; ++t) {
        // prefetch next step's xg (stays in flight across the raw barrier)
        float nr = 0.f, nz = 0.f, nn_ = 0.f;
        if (t + 1 < TT) {
            const float* xpn = xp + gstep;
            nr  = xpn[0];
            nz  = xpn[128];
            nn_ = xpn[256];
        }

        // MFMA: per gate, 3 independent 4-chains (hi*hi, lo*hi, hi*lo)
        float gate[3];
        #pragma unroll
        for (int g = 0; g < 3; ++g) {
            f32x4 u = {0.f, 0.f, 0.f, 0.f};
            f32x4 v = {0.f, 0.f, 0.f, 0.f};
            f32x4 w4 = {0.f, 0.f, 0.f, 0.f};
            #pragma unroll
            for (int ch = 0; ch < 4; ++ch) {
                u  = __builtin_amdgcn_mfma_f32_16x16x32_bf16(ahi[ch], bhi[g][ch], u, 0, 0, 0);
                v  = __builtin_amdgcn_mfma_f32_16x16x32_bf16(alo[ch], bhi[g][ch], v, 0, 0, 0);
                w4 = __builtin_amdgcn_mfma_f32_16x16x32_bf16(ahi[ch], blo[g][ch], w4, 0, 0, 0);
            }
            gate[g] = u[0] + v[0] + w4[0];   // all C rows identical; take reg 0
        }

        // gates + h update (computed redundantly in all lanes of the wave)
        float pr = gate[0] + xr + bias[0];
        float pz = gate[1] + xz + bias[1];
        float pm = gate[2] + bias[2];
        float rg = fast_sigmoid(pr);
        float zg = fast_sigmoid(pz);
        float ng = fast_tanh(xn + rg * pm);
        float hn = (1.f - zg) * ng + zg * ho;
        ho = hn;

        const int pb = (t + 1) & 1;
        if (q == 0) {
            *op = hn;                         // global store, 16 lanes/wave
            u16 hi = f2bf(hn);
            u16 lo = f2bf(hn - bf2f(hi));
            hhi[pb][hcol] = hi;
            hlo[pb][hcol] = lo;
        }

        // drain LDS writes only, then barrier (vmcnt stays outstanding)
        asm volatile("s_waitcnt lgkmcnt(0)\n\ts_barrier" ::: "memory");

        if (t + 1 < TT) {
            #pragma unroll
            for (int ch = 0; ch < 4; ++ch) {
                ahi[ch] = *(const short8*)(&hhi[pb][ch * 32 + q * 8]);
                alo[ch] = *(const short8*)(&hlo[pb][ch * 32 + q * 8]);
            }
            xr = nr; xz = nz; xn = nn_;
            xp += gstep;
            op += ostep;
        }
    }
}

// ---------------- Launch ----------------
// ws: XG only = 2*65536*384*4 = 201.3 MB. Inter-layer activations ping-pong
// through d_out (each layer fully rewrites it before the next reads it).
extern "C" void kernel_launch(void* const* d_in, const int* in_sizes, int n_in,
                              void* d_out, int out_size, void* d_ws, size_t ws_size,
                              hipStream_t stream) {
    const float* x  = (const float*)d_in[0];   // [16,4096,256]
    const float* Wi = (const float*)d_in[1];   // [3,2,256,384]
    const float* Wh = (const float*)d_in[2];   // [3,2,128,384]
    const float* bh = (const float*)d_in[3];   // [3,2,384]
    float* out = (float*)d_out;                // [16,4096,256]

    float* XG = (float*)d_ws;                  // [2, 65536, 384] fp32

    for (int l = 0; l < 3; ++l) {
        const float* in  = (l == 0) ? x : out;
        const float* Wil = Wi + (size_t)l * 2 * DD * G3;
        const float* Whl = Wh + (size_t)l * 2 * HH * G3;
        const float* bhl = bh + (size_t)l * 2 * G3;

        gemm_in<<<dim3(6, MM / Bb), 256, 0, stream>>>(in, Wil, XG);
        gru_rec<<<32, 512, 0, stream>>>(XG, Whl, bhl, out);
    }
}

// Round 6
// 7584.403 us; speedup vs baseline: 2.0104x; 1.3469x over previous
//
#include <hip/hip_runtime.h>

// Problem constants
#define BB 16
#define TT 4096
#define DD 256     // DIM
#define HH 128     // hidden
#define G3 384     // 3*H
#define MM (BB*TT) // 65536 rows

typedef unsigned short u16;
typedef unsigned int u32;
typedef __attribute__((ext_vector_type(8))) short short8;  // 8 bf16 (4 VGPRs)
typedef __attribute__((ext_vector_type(4))) float f32x4;

__device__ __forceinline__ float bf2f(u16 u) {
    return __uint_as_float(((u32)u) << 16);
}
__device__ __forceinline__ u16 f2bf(float f) {
    u32 u = __float_as_uint(f);
    u32 lsb = (u >> 16) & 1u;
    u += 0x7fffu + lsb;      // RNE
    return (u16)(u >> 16);
}

// ---------------- Input-projection GEMM (fp32) ----------------
// XG[dir][m][0:384] = X[m][0:256] @ Wi[dir][0:256][0:384]
#define Bb 128
#define Bn 128
#define Bk 16

__global__ __launch_bounds__(256) void gemm_in(const float* __restrict__ X,
                                               const float* __restrict__ Wi,
                                               float* __restrict__ XG) {
    __shared__ __align__(16) float As[Bk][Bb + 4];
    __shared__ __align__(16) float Bs[Bk][Bn + 4];
    const int tid = threadIdx.x;
    const int m0  = blockIdx.y * Bb;
    const int nb  = blockIdx.x;
    const int n0  = nb * Bn;
    const int dir = (n0 >= G3) ? 1 : 0;
    const int nloc0 = n0 - dir * G3;
    const float* Wd = Wi + (size_t)dir * DD * G3;

    const int tx = tid & 15;
    const int ty = tid >> 4;
    float acc[8][8];
    #pragma unroll
    for (int i = 0; i < 8; ++i)
        #pragma unroll
        for (int j = 0; j < 8; ++j) acc[i][j] = 0.f;

    for (int k0 = 0; k0 < DD; k0 += Bk) {
        #pragma unroll
        for (int p = 0; p < 2; ++p) {
            int idx = tid + p * 256;
            int row = idx >> 2;
            int c4  = (idx & 3) * 4;
            float4 v = *(const float4*)(X + (size_t)(m0 + row) * DD + k0 + c4);
            As[c4 + 0][row] = v.x;
            As[c4 + 1][row] = v.y;
            As[c4 + 2][row] = v.z;
            As[c4 + 3][row] = v.w;
        }
        #pragma unroll
        for (int p = 0; p < 2; ++p) {
            int idx  = tid + p * 256;
            int krow = idx >> 5;
            int c4   = (idx & 31) * 4;
            float4 v = *(const float4*)(Wd + (size_t)(k0 + krow) * G3 + nloc0 + c4);
            *(float4*)(&Bs[krow][c4]) = v;
        }
        __syncthreads();
        #pragma unroll
        for (int k = 0; k < Bk; ++k) {
            float4 a0 = *(const float4*)(&As[k][ty * 8]);
            float4 a1 = *(const float4*)(&As[k][ty * 8 + 4]);
            float4 b0 = *(const float4*)(&Bs[k][tx * 8]);
            float4 b1 = *(const float4*)(&Bs[k][tx * 8 + 4]);
            float av[8] = {a0.x, a0.y, a0.z, a0.w, a1.x, a1.y, a1.z, a1.w};
            float bv[8] = {b0.x, b0.y, b0.z, b0.w, b1.x, b1.y, b1.z, b1.w};
            #pragma unroll
            for (int i = 0; i < 8; ++i)
                #pragma unroll
                for (int j = 0; j < 8; ++j) acc[i][j] += av[i] * bv[j];
        }
        __syncthreads();
    }
    #pragma unroll
    for (int i = 0; i < 8; ++i) {
        int m = m0 + ty * 8 + i;
        float* dst = XG + ((size_t)dir * MM + m) * G3 + nloc0 + tx * 8;
        *(float4*)dst       = make_float4(acc[i][0], acc[i][1], acc[i][2], acc[i][3]);
        *(float4*)(dst + 4) = make_float4(acc[i][4], acc[i][5], acc[i][6], acc[i][7]);
    }
}

// ---------------- MFMA recurrence, one WG per (dir,batch) ----------------
__device__ __forceinline__ float fast_sigmoid(float x) {
    float e = __expf(-x);
    return __builtin_amdgcn_rcpf(1.f + e);
}
__device__ __forceinline__ float fast_tanh(float x) {
    float e = __expf(2.f * x);
    return 1.f - 2.f * __builtin_amdgcn_rcpf(1.f + e);
}

// grid = 32 (dir,batch); block = 512 (8 waves). Wave w owns hcol slice
// [16w,16w+16) for all 3 gates (n = g*128 + hcol).
// Row-split hi/lo trick: A rows 0-7 carry h_hi, rows 8-15 carry h_lo, so ONE
// MFMA chain per gate yields h_hi@W in quads 0-1 and h_lo@W in quads 2-3;
// __shfl_xor(.,32)+add recombines -> h at ~fp32 precision with 1/3 the MFMAs
// of round 5 (96/step/CU ~ 466 cyc, the measured round-5 bottleneck).
// Wh is plain bf16 (only numerics change vs round 5).
__global__ __launch_bounds__(512, 2) void gru_rec(const float* __restrict__ XG,
                                                  const float* __restrict__ Wh,
                                                  const float* __restrict__ bh,
                                                  float* __restrict__ Xout) {
    const int wg   = blockIdx.x;     // 0..31
    const int dir  = wg & 1;
    const int b    = wg >> 1;
    const int tid  = threadIdx.x;
    const int lane = tid & 63;
    const int wave = tid >> 6;       // 0..7
    const int q    = lane >> 4;      // 0..3
    const int c    = lane & 15;
    const int hcol = wave * 16 + c;  // 0..127

    __shared__ __align__(16) u16 hhi[2][HH];   // ping-pong, bf16 hi
    __shared__ __align__(16) u16 hlo[2][HH];   // bf16 lo (residual)

    // ---- B-frag preload (Wh), plain bf16 ----
    // B layout (16x16x32): n = lane&15, k = (lane>>4)*8 + j
    short8 bfr[3][4];
    const float* W = Wh + (size_t)dir * HH * G3;
    #pragma unroll
    for (int g = 0; g < 3; ++g) {
        const int n = g * 128 + hcol;
        #pragma unroll
        for (int ch = 0; ch < 4; ++ch) {
            short8 vh;
            #pragma unroll
            for (int j = 0; j < 8; ++j) {
                int k = ch * 32 + q * 8 + j;
                vh[j] = (short)f2bf(W[(size_t)k * G3 + n]);
            }
            bfr[ch][0]; // no-op to keep indices clear
            bfr[g][ch] = vh;
        }
    }
    float bias[3];
    #pragma unroll
    for (int g = 0; g < 3; ++g) bias[g] = bh[dir * G3 + g * 128 + hcol];

    // A-frags: rows 0-7 = h_hi, rows 8-15 = h_lo. Lane's row m = c; so lanes
    // c<8 load from hhi, c>=8 from hlo. Zero at t=0.
    short8 a[4];
    #pragma unroll
    for (int ch = 0; ch < 4; ++ch)
        #pragma unroll
        for (int j = 0; j < 8; ++j) a[ch][j] = 0;
    float ho = 0.f;                  // h_old at this wave's column hcol (fp32)

    const int t0    = dir ? (TT - 1) : 0;
    const int gstep = dir ? -G3 : G3;   // xg pointer step (floats)
    const int ostep = dir ? -DD : DD;   // out pointer step (floats)

    const float* xp = XG + ((size_t)dir * MM + (size_t)b * TT + t0) * G3 + hcol;
    float* op = Xout + ((size_t)b * TT + t0) * DD + dir * HH + hcol;

    // depth-2 xg prefetch ring (step ~600 cyc < HBM latency ~900 cyc)
    float xr0 = xp[0], xz0 = xp[128], xn0 = xp[256];
    const float* xp1 = xp + gstep;
    float xr1 = xp1[0], xz1 = xp1[128], xn1 = xp1[256];

    for (int t = 0; t < TT; ++t) {
        // prefetch t+2 (stays in flight across the raw barrier)
        float nr = 0.f, nz = 0.f, nn_ = 0.f;
        if (t + 2 < TT) {
            const float* p2 = xp + 2 * gstep;
            nr  = p2[0];
            nz  = p2[128];
            nn_ = p2[256];
        }

        // MFMA: one chain of 4 per gate (3 independent chains/wave)
        f32x4 acc0 = {0.f, 0.f, 0.f, 0.f};
        f32x4 acc1 = {0.f, 0.f, 0.f, 0.f};
        f32x4 acc2 = {0.f, 0.f, 0.f, 0.f};
        #pragma unroll
        for (int ch = 0; ch < 4; ++ch) {
            acc0 = __builtin_amdgcn_mfma_f32_16x16x32_bf16(a[ch], bfr[0][ch], acc0, 0, 0, 0);
            acc1 = __builtin_amdgcn_mfma_f32_16x16x32_bf16(a[ch], bfr[1][ch], acc1, 0, 0, 0);
            acc2 = __builtin_amdgcn_mfma_f32_16x16x32_bf16(a[ch], bfr[2][ch], acc2, 0, 0, 0);
        }
        // reg0 = row q*4: quads 0-1 hold h_hi@W, quads 2-3 hold h_lo@W.
        // shfl_xor(32) swaps q0<->q2, q1<->q3 -> every lane gets hi+lo.
        float g0 = acc0[0], g1 = acc1[0], g2 = acc2[0];
        float gate0 = g0 + __shfl_xor(g0, 32);
        float gate1 = g1 + __shfl_xor(g1, 32);
        float gate2 = g2 + __shfl_xor(g2, 32);

        // gates + h update (all lanes identical per column)
        float pr = gate0 + xr0 + bias[0];
        float pz = gate1 + xz0 + bias[1];
        float pm = gate2 + bias[2];
        float rg = fast_sigmoid(pr);
        float zg = fast_sigmoid(pz);
        float ng = fast_tanh(xn0 + rg * pm);
        float hn = (1.f - zg) * ng + zg * ho;
        ho = hn;

        const int pb = (t + 1) & 1;
        u16 hi = f2bf(hn);
        if (q == 0) {
            *op = hn;                         // global store, 16 lanes/wave
            hhi[pb][hcol] = hi;
        } else if (q == 1) {
            hlo[pb][hcol] = f2bf(hn - bf2f(hi));
        }

        // drain LDS writes only, then barrier (vmcnt stays outstanding)
        asm volatile("s_waitcnt lgkmcnt(0)\n\ts_barrier" ::: "memory");

        if (t + 1 < TT) {
            const u16* hp = (c < 8) ? &hhi[pb][0] : &hlo[pb][0];
            #pragma unroll
            for (int ch = 0; ch < 4; ++ch)
                a[ch] = *(const short8*)(hp + ch * 32 + q * 8);
            xr0 = xr1; xz0 = xz1; xn0 = xn1;
            xr1 = nr;  xz1 = nz;  xn1 = nn_;
            xp += gstep;
            op += ostep;
        }
    }
}

// ---------------- Launch ----------------
// ws: XG only = 2*65536*384*4 = 201.3 MB. Inter-layer activations ping-pong
// through d_out (each layer fully rewrites it before the next reads it).
extern "C" void kernel_launch(void* const* d_in, const int* in_sizes, int n_in,
                              void* d_out, int out_size, void* d_ws, size_t ws_size,
                              hipStream_t stream) {
    const float* x  = (const float*)d_in[0];   // [16,4096,256]
    const float* Wi = (const float*)d_in[1];   // [3,2,256,384]
    const float* Wh = (const float*)d_in[2];   // [3,2,128,384]
    const float* bh = (const float*)d_in[3];   // [3,2,384]
    float* out = (float*)d_out;                // [16,4096,256]

    float* XG = (float*)d_ws;                  // [2, 65536, 384] fp32

    for (int l = 0; l < 3; ++l) {
        const float* in  = (l == 0) ? x : out;
        const float* Wil = Wi + (size_t)l * 2 * DD * G3;
        const float* Whl = Wh + (size_t)l * 2 * HH * G3;
        const float* bhl = bh + (size_t)l * 2 * G3;

        gemm_in<<<dim3(6, MM / Bb), 256, 0, stream>>>(in, Wil, XG);
        gru_rec<<<32, 512, 0, stream>>>(XG, Whl, bhl, out);
    }
}